// Round 1
// baseline (520.845 us; speedup 1.0000x reference)
//
#include <hip/hip_runtime.h>

// Problem constants (from reference): B=4, H=32, BLOCK=4096, D=128, S=1024
#define B_DIM  4
#define H_DIM  32
#define BLOCKC 4096
#define D_DIM  128
#define S_LEN  1024
#define BH     (B_DIM * H_DIM)        // 128
#define D4     (D_DIM / 4)            // 32 float4 per row
#define N4_PER (BH * S_LEN * D4)      // 4,194,304 float4 per output tensor

__global__ void init_inv_kernel(int* __restrict__ inv) {
    int i = blockIdx.x * blockDim.x + threadIdx.x;
    if (i < S_LEN) inv[i] = -1;
}

__global__ void scatter_inv_kernel(const int* __restrict__ pos, int* __restrict__ inv) {
    int s = blockIdx.x * blockDim.x + threadIdx.x;
    if (s < S_LEN) {
        int p = pos[s];
        if (p >= 0 && p < S_LEN) inv[p] = s;   // last-writer semantics; arange => bijective
    }
}

// out layout: [2][BH][S][D]  (k slice then v slice), float32
// val layout: [BH][S][D]; cache layout: [BH][BLOCK][D]
__global__ void __launch_bounds__(256) gather_kv_kernel(
        const float4* __restrict__ k_val,
        const float4* __restrict__ v_val,
        const float4* __restrict__ k_cache,
        const float4* __restrict__ v_cache,
        const int*    __restrict__ inv,
        float4*       __restrict__ out) {
    const int total = 2 * N4_PER;                       // 8,388,608 < 2^31
    const int stride = gridDim.x * blockDim.x;
    for (int i = blockIdx.x * blockDim.x + threadIdx.x; i < total; i += stride) {
        int tensor = i >= N4_PER;                       // 0 = k, 1 = v
        int j = i - (tensor << 22);                     // j in [0, N4_PER); N4_PER = 1<<22
        int d4  = j & (D4 - 1);                         // j & 31
        int row = j >> 5;                               // bh*S + p
        int p   = row & (S_LEN - 1);
        int bh  = row >> 10;
        int s   = inv[p];                               // L1/L2-resident (4 KB)
        float4 v;
        if (s >= 0) {
            const float4* src = tensor ? v_val : k_val;
            v = src[(bh << 10 | s) * D4 + d4];          // (bh*S + s)*D4 + d4
        } else {
            const float4* src = tensor ? v_cache : k_cache;
            v = src[(bh << 12 | p) * D4 + d4];          // (bh*BLOCK + p)*D4 + d4
        }
        out[i] = v;
    }
}

extern "C" void kernel_launch(void* const* d_in, const int* in_sizes, int n_in,
                              void* d_out, int out_size, void* d_ws, size_t ws_size,
                              hipStream_t stream) {
    const int*    pos     = (const int*)   d_in[0];
    const float4* k_val   = (const float4*)d_in[1];
    const float4* v_val   = (const float4*)d_in[2];
    const float4* k_cache = (const float4*)d_in[3];
    const float4* v_cache = (const float4*)d_in[4];
    float4* out = (float4*)d_out;
    int*    inv = (int*)d_ws;                 // S_LEN ints = 4 KB scratch

    init_inv_kernel<<<(S_LEN + 255) / 256, 256, 0, stream>>>(inv);
    scatter_inv_kernel<<<(S_LEN + 255) / 256, 256, 0, stream>>>(pos, inv);

    // 8,388,608 float4 total; 4096 blocks x 256 threads -> 8 f4 per thread
    gather_kv_kernel<<<4096, 256, 0, stream>>>(k_val, v_val, k_cache, v_cache, inv, out);
}

// Round 3
// 518.472 us; speedup vs baseline: 1.0046x; 1.0046x over previous
//
#include <hip/hip_runtime.h>

// Problem constants (from reference): B=4, H=32, BLOCK=4096, D=128, S=1024
#define B_DIM  4
#define H_DIM  32
#define BLOCKC 4096
#define D_DIM  128
#define S_LEN  1024
#define BH     (B_DIM * H_DIM)        // 128
#define D4     (D_DIM / 4)            // 32 float4 per row
#define N4_PER (BH * S_LEN * D4)      // 4,194,304 float4 per output tensor (1<<22)

// Single fused kernel: each block rebuilds the S->slot inverse map in LDS
// (pos is 4 KB, L2-resident across blocks), then gathers both outputs with
// fully coalesced float4 loads/stores.
//
// out layout: [2][BH][S][D]  (k slice then v slice), float32
// val layout: [BH][S][D]; cache layout: [BH][BLOCK][D]
__global__ void __launch_bounds__(256) fused_kv_kernel(
        const int*    __restrict__ pos,
        const float4* __restrict__ k_val,
        const float4* __restrict__ v_val,
        const float4* __restrict__ k_cache,
        const float4* __restrict__ v_cache,
        float4*       __restrict__ out) {
    __shared__ int inv[S_LEN];

    #pragma unroll
    for (int t = threadIdx.x; t < S_LEN; t += 256) inv[t] = -1;
    __syncthreads();
    #pragma unroll
    for (int t = threadIdx.x; t < S_LEN; t += 256) {
        int p = pos[t];
        if (p >= 0 && p < S_LEN) inv[p] = t;   // arange => bijective in practice
    }
    __syncthreads();

    const int total  = 2 * N4_PER;              // 8,388,608 float4
    const int stride = gridDim.x * blockDim.x;
    for (int i = blockIdx.x * blockDim.x + threadIdx.x; i < total; i += stride) {
        int tensor = i >= N4_PER;               // 0 = k, 1 = v (wave-uniform)
        int j   = i & (N4_PER - 1);
        int d4  = j & (D4 - 1);                 // j & 31
        int row = j >> 5;                       // bh*S + p
        int p   = row & (S_LEN - 1);
        int bh  = row >> 10;
        int s   = inv[p];                       // LDS broadcast (2 rows per wave)
        float4 v;
        if (s >= 0) {
            const float4* src = tensor ? v_val : k_val;
            v = src[((bh << 10) | s) * D4 + d4];   // (bh*S + s)*D4 + d4
        } else {
            const float4* src = tensor ? v_cache : k_cache;
            v = src[((bh << 12) | p) * D4 + d4];   // (bh*BLOCK + p)*D4 + d4
        }
        out[i] = v;
    }
}

extern "C" void kernel_launch(void* const* d_in, const int* in_sizes, int n_in,
                              void* d_out, int out_size, void* d_ws, size_t ws_size,
                              hipStream_t stream) {
    const int*    pos     = (const int*)   d_in[0];
    const float4* k_val   = (const float4*)d_in[1];
    const float4* v_val   = (const float4*)d_in[2];
    const float4* k_cache = (const float4*)d_in[3];
    const float4* v_cache = (const float4*)d_in[4];
    float4* out = (float4*)d_out;

    // 2048 blocks x 256 threads = 32 waves/CU (max occupancy); 16 float4/thread.
    fused_kv_kernel<<<2048, 256, 0, stream>>>(pos, k_val, v_val, k_cache, v_cache, out);
}